// Round 4
// baseline (141.755 us; speedup 1.0000x reference)
//
#include <hip/hip_runtime.h>

// Problem constants
#define BB 4
#define SS 2048
#define DM 256
#define NH 4
#define DH 64
#define NROW (BB*SS)          // 8192
#define NE   (3*DM)           // 768
#define HEAD_ELEMS (BB*NH*SS*DH)  // 2097152 per tensor

typedef _Float16 half_t;
typedef __attribute__((ext_vector_type(8))) _Float16 half8;
typedef __attribute__((ext_vector_type(4))) _Float16 half4;
typedef __attribute__((ext_vector_type(4))) float floatx4;

#define KPAD 72               // fp16 LDS stride (64 + 8 halfs = 144 B, 16B-aligned rows)

// ---------------------------------------------------------------------------
// QKV projection, fp16 MFMA with x = x_hi + x_lo split (W single fp16).
// Epilogue: q/k scatter direct (2B stores, contiguous per 16 lanes);
// v-tiles (block-uniform part) transpose through LDS (reusing Xh) and exit
// as coalesced half8 stores into vt[B,H,DH,S].
// ---------------------------------------------------------------------------
__global__ __launch_bounds__(256) void qkv_proj(const float* __restrict__ x,
                                                const float* __restrict__ W,
                                                const float* __restrict__ bias,
                                                half_t* __restrict__ qh,
                                                half_t* __restrict__ kh,
                                                half_t* __restrict__ vt) {
    __shared__ __align__(16) half_t Xh[64 * KPAD];  // x hi,  [m][k]  (reused for v^T)
    __shared__ __align__(16) half_t Xl[64 * KPAD];  // x lo,  [m][k]
    __shared__ __align__(16) half_t Wh[64 * KPAD];  // W fp16,[n][k]

    const int rb   = blockIdx.x * 64;   // row base (b*s)
    const int nb   = blockIdx.y * 64;   // feature base
    const int tid  = threadIdx.x;
    const int wid  = tid >> 6;
    const int lane = tid & 63;
    const int quad = lane >> 4;
    const int col  = lane & 15;

    floatx4 acc[4];
    #pragma unroll
    for (int t = 0; t < 4; ++t) acc[t] = (floatx4){0.f, 0.f, 0.f, 0.f};

    for (int k0 = 0; k0 < DM; k0 += 64) {
        __syncthreads();
        #pragma unroll
        for (int i = 0; i < 4; ++i) {
            int idx = tid + 256 * i;       // 0..1023
            int r   = idx >> 4;            // 0..63
            int c4  = (idx & 15) * 4;      // 0..60
            float4 vx = *(const float4*)&x[(size_t)(rb + r) * DM + k0 + c4];
            half4 hx, lx;
            hx.x = (half_t)vx.x; lx.x = (half_t)(vx.x - (float)hx.x);
            hx.y = (half_t)vx.y; lx.y = (half_t)(vx.y - (float)hx.y);
            hx.z = (half_t)vx.z; lx.z = (half_t)(vx.z - (float)hx.z);
            hx.w = (half_t)vx.w; lx.w = (half_t)(vx.w - (float)hx.w);
            *(half4*)&Xh[r * KPAD + c4] = hx;
            *(half4*)&Xl[r * KPAD + c4] = lx;
            float4 vw = *(const float4*)&W[(size_t)(nb + r) * DM + k0 + c4];
            half4 hw;
            hw.x = (half_t)vw.x; hw.y = (half_t)vw.y;
            hw.z = (half_t)vw.z; hw.w = (half_t)vw.w;
            *(half4*)&Wh[r * KPAD + c4] = hw;
        }
        __syncthreads();

        half8 ah0 = *(const half8*)&Xh[(wid * 16 + col) * KPAD + quad * 8];
        half8 ah1 = *(const half8*)&Xh[(wid * 16 + col) * KPAD + 32 + quad * 8];
        half8 al0 = *(const half8*)&Xl[(wid * 16 + col) * KPAD + quad * 8];
        half8 al1 = *(const half8*)&Xl[(wid * 16 + col) * KPAD + 32 + quad * 8];

        #pragma unroll
        for (int t = 0; t < 4; ++t) {
            half8 bh0 = *(const half8*)&Wh[(t * 16 + col) * KPAD + quad * 8];
            half8 bh1 = *(const half8*)&Wh[(t * 16 + col) * KPAD + 32 + quad * 8];
            acc[t] = __builtin_amdgcn_mfma_f32_16x16x32_f16(ah0, bh0, acc[t], 0, 0, 0);
            acc[t] = __builtin_amdgcn_mfma_f32_16x16x32_f16(ah1, bh1, acc[t], 0, 0, 0);
            acc[t] = __builtin_amdgcn_mfma_f32_16x16x32_f16(al0, bh0, acc[t], 0, 0, 0);
            acc[t] = __builtin_amdgcn_mfma_f32_16x16x32_f16(al1, bh1, acc[t], 0, 0, 0);
        }
    }

    // Epilogue. part is block-uniform (nb is a multiple of 64, sections of 256).
    const int part  = nb >> 8;          // 0=q 1=k 2=v
    const int mloc  = wid * 16 + quad * 4;
    if (part != 2) {
        #pragma unroll
        for (int t = 0; t < 4; ++t) {
            int e    = nb + t * 16 + col;
            float be = bias[e];
            int dm   = e & 255;
            int h    = dm >> 6;
            int dh   = dm & 63;
            #pragma unroll
            for (int r = 0; r < 4; ++r) {
                int row = rb + mloc + r;
                int b   = row >> 11;
                int s   = row & 2047;
                int bh_ = b * NH + h;
                float val = acc[t][r] + be;
                if (part == 0) {
                    qh[((size_t)bh_ * SS + s) * DH + dh] = (half_t)(val * 0.125f);
                } else {
                    kh[((size_t)bh_ * SS + s) * DH + dh] = (half_t)val;
                }
            }
        }
    } else {
        // Transpose v tile through LDS (Xh is dead) -> coalesced vt stores.
        __syncthreads();
        #pragma unroll
        for (int t = 0; t < 4; ++t) {
            int e    = nb + t * 16 + col;
            float be = bias[e];
            #pragma unroll
            for (int r = 0; r < 4; ++r)
                Xh[(t * 16 + col) * KPAD + mloc + r] = (half_t)(acc[t][r] + be);
        }
        __syncthreads();
        const int b   = rb >> 11;
        const int s0  = rb & 2047;
        const int h   = (nb >> 6) & 3;
        const int bh_ = b * NH + h;
        #pragma unroll
        for (int i = 0; i < 2; ++i) {
            int idx = tid + 256 * i;   // 0..511
            int rr  = idx >> 3;        // dh 0..63
            int cc8 = (idx & 7) * 8;   // s chunk
            *(half8*)&vt[((size_t)bh_ * DH + rr) * SS + s0 + cc8] =
                *(const half8*)&Xh[rr * KPAD + cc8];
        }
    }
}

// ---------------------------------------------------------------------------
// Flash attention, fp16 MFMA, S^T trick.
// Block = 128 thr (2 waves), 32 q rows -> 1024 blocks (4/CU).
// K/V tiles register-double-buffered: prefetch tile kt+64 into regs after the
// second barrier (loads stay in flight across the whole compute phase).
// ---------------------------------------------------------------------------
__global__ __launch_bounds__(128) void attn(const half_t* __restrict__ qh,
                                            const half_t* __restrict__ kh,
                                            const half_t* __restrict__ vt,
                                            float* __restrict__ out) {
    __shared__ __align__(16) half_t Ks[64 * KPAD];    // [kr][d]
    __shared__ __align__(16) half_t Vts[64 * KPAD];   // [d][kr]

    const int q0   = blockIdx.x * 32;
    const int bh   = blockIdx.y;
    const size_t base = (size_t)bh * SS * DH;
    const int tid  = threadIdx.x;
    const int wid  = tid >> 6;    // 0..1
    const int lane = tid & 63;
    const int quad = lane >> 4;
    const int col  = lane & 15;

    // Staging indices (4 chunks per thread cover 512 half8 = K+V tiles)
    int srr[4], scc[4];
    #pragma unroll
    for (int i = 0; i < 4; ++i) {
        int gi = tid + 128 * i;    // 0..511
        srr[i] = gi >> 3;          // 0..63
        scc[i] = (gi & 7) * 8;     // 0..56
    }

    // Q B-frags, resident all kernel (pre-scaled by 0.125 in qkv_proj)
    half8 bq0, bq1;
    {
        int s = q0 + wid * 16 + col;
        bq0 = *(const half8*)&qh[base + (size_t)s * DH + quad * 8];
        bq1 = *(const half8*)&qh[base + (size_t)s * DH + 32 + quad * 8];
    }

    // Preload tile 0 into cur regs
    half8 ck[4], cv[4], nk[4], nv[4];
    #pragma unroll
    for (int i = 0; i < 4; ++i) {
        ck[i] = *(const half8*)&kh[base + (size_t)srr[i] * DH + scc[i]];
        cv[i] = *(const half8*)&vt[base + (size_t)srr[i] * SS + scc[i]];
    }

    float m_i = -3.0e38f;
    float l_i = 0.0f;
    floatx4 o[4];
    #pragma unroll
    for (int dt = 0; dt < 4; ++dt) o[dt] = (floatx4){0.f, 0.f, 0.f, 0.f};

    for (int kt = 0; kt < SS; kt += 64) {
        __syncthreads();   // previous compute done reading LDS
        #pragma unroll
        for (int i = 0; i < 4; ++i) {
            *(half8*)&Ks[srr[i] * KPAD + scc[i]]  = ck[i];
            *(half8*)&Vts[srr[i] * KPAD + scc[i]] = cv[i];
        }
        __syncthreads();   // tiles visible to all waves

        // Prefetch next tile; loads stay in flight across compute.
        const int ktn = kt + 64;
        if (ktn < SS) {
            #pragma unroll
            for (int i = 0; i < 4; ++i) {
                nk[i] = *(const half8*)&kh[base + (size_t)(ktn + srr[i]) * DH + scc[i]];
                nv[i] = *(const half8*)&vt[base + (size_t)srr[i] * SS + ktn + scc[i]];
            }
        }

        // S^T = K · Q^T
        floatx4 sc[4];
        #pragma unroll
        for (int t = 0; t < 4; ++t) {
            half8 ak0 = *(const half8*)&Ks[(t * 16 + col) * KPAD + quad * 8];
            half8 ak1 = *(const half8*)&Ks[(t * 16 + col) * KPAD + 32 + quad * 8];
            floatx4 c = (floatx4){0.f, 0.f, 0.f, 0.f};
            c = __builtin_amdgcn_mfma_f32_16x16x32_f16(ak0, bq0, c, 0, 0, 0);
            c = __builtin_amdgcn_mfma_f32_16x16x32_f16(ak1, bq1, c, 0, 0, 0);
            sc[t] = c;
        }

        // Online softmax (lane owns one q column)
        float mloc = -3.0e38f;
        #pragma unroll
        for (int t = 0; t < 4; ++t)
            #pragma unroll
            for (int r = 0; r < 4; ++r)
                mloc = fmaxf(mloc, sc[t][r]);
        mloc = fmaxf(mloc, __shfl_xor(mloc, 16));
        mloc = fmaxf(mloc, __shfl_xor(mloc, 32));
        float m_new = fmaxf(m_i, mloc);
        float alpha = __expf(m_i - m_new);
        m_i = m_new;

        float rsum = 0.f;
        half4 pa[4];
        #pragma unroll
        for (int t = 0; t < 4; ++t) {
            float p0 = __expf(sc[t][0] - m_new);
            float p1 = __expf(sc[t][1] - m_new);
            float p2 = __expf(sc[t][2] - m_new);
            float p3 = __expf(sc[t][3] - m_new);
            rsum += p0 + p1 + p2 + p3;
            pa[t] = (half4){(half_t)p0, (half_t)p1, (half_t)p2, (half_t)p3};
        }
        rsum += __shfl_xor(rsum, 16);
        rsum += __shfl_xor(rsum, 32);
        l_i = l_i * alpha + rsum;

        float ar[4];
        #pragma unroll
        for (int i = 0; i < 4; ++i) ar[i] = __shfl(alpha, quad * 4 + i);
        #pragma unroll
        for (int dt = 0; dt < 4; ++dt)
            #pragma unroll
            for (int i = 0; i < 4; ++i)
                o[dt][i] *= ar[i];

        // O += P · V
        #pragma unroll
        for (int t = 0; t < 4; ++t) {
            #pragma unroll
            for (int dt = 0; dt < 4; ++dt) {
                half4 bv = *(const half4*)&Vts[(dt * 16 + col) * KPAD + t * 16 + quad * 4];
                o[dt] = __builtin_amdgcn_mfma_f32_16x16x16f16(pa[t], bv, o[dt], 0, 0, 0);
            }
        }

        #pragma unroll
        for (int i = 0; i < 4; ++i) { ck[i] = nk[i]; cv[i] = nv[i]; }
    }

    // Epilogue: normalize, store fp32 [bh][s][d]
    float inv = 1.0f / l_i;
    float ir[4];
    #pragma unroll
    for (int i = 0; i < 4; ++i) ir[i] = __shfl(inv, quad * 4 + i);
    #pragma unroll
    for (int dt = 0; dt < 4; ++dt)
        #pragma unroll
        for (int i = 0; i < 4; ++i)
            out[base + (size_t)(q0 + wid * 16 + quad * 4 + i) * DH + dt * 16 + col] = o[dt][i] * ir[i];
}

extern "C" void kernel_launch(void* const* d_in, const int* in_sizes, int n_in,
                              void* d_out, int out_size, void* d_ws, size_t ws_size,
                              hipStream_t stream) {
    const float* x  = (const float*)d_in[0];   // [4,2048,256]
    const float* Wq = (const float*)d_in[1];   // [768,256]
    const float* bq = (const float*)d_in[2];   // [768]
    float* out = (float*)d_out;                // [4,4,2048,64]

    half_t* qh = (half_t*)d_ws;                        // [B,H,S,DH] fp16, pre-scaled
    half_t* kh = qh + (size_t)HEAD_ELEMS;              // [B,H,S,DH] fp16
    half_t* vt = kh + (size_t)HEAD_ELEMS;              // [B,H,DH,S] fp16

    qkv_proj<<<dim3(NROW / 64, NE / 64), 256, 0, stream>>>(x, Wq, bq, qh, kh, vt);
    attn<<<dim3(SS / 32, BB * NH), 128, 0, stream>>>(qh, kh, vt, out);
}

// Round 5
// 120.626 us; speedup vs baseline: 1.1752x; 1.1752x over previous
//
#include <hip/hip_runtime.h>

// Problem constants
#define BB 4
#define SS 2048
#define DM 256
#define NH 4
#define DH 64
#define NROW (BB*SS)              // 8192
#define NE   (3*DM)               // 768
#define BH   (BB*NH)              // 16
#define HEAD_ELEMS (BH*SS*DH)     // 2097152 per tensor
#define NQROWS (BH*SS)            // 32768

typedef _Float16 half_t;
typedef __attribute__((ext_vector_type(8))) _Float16 half8;
typedef __attribute__((ext_vector_type(4))) _Float16 half4;
typedef __attribute__((ext_vector_type(4))) float floatx4;

#define KPAD 72                   // LDS stride in halfs (144 B, 16B-aligned rows)

// ---------------------------------------------------------------------------
// prep: one-shot conversion  x -> (x_hi, x_lo) fp16,  W -> fp16.
// grid 2048 x 256: thread gtid handles x[gtid*4..+3]; first 49152 also W.
// ---------------------------------------------------------------------------
__global__ __launch_bounds__(256) void prep(const float* __restrict__ x,
                                            const float* __restrict__ W,
                                            half_t* __restrict__ xh,
                                            half_t* __restrict__ xl,
                                            half_t* __restrict__ wh) {
    int gtid = blockIdx.x * 256 + threadIdx.x;    // 0..524287
    {
        int i = gtid * 4;
        float4 v = *(const float4*)&x[i];
        half4 h, l;
        h.x = (half_t)v.x; l.x = (half_t)(v.x - (float)h.x);
        h.y = (half_t)v.y; l.y = (half_t)(v.y - (float)h.y);
        h.z = (half_t)v.z; l.z = (half_t)(v.z - (float)h.z);
        h.w = (half_t)v.w; l.w = (half_t)(v.w - (float)h.w);
        *(half4*)&xh[i] = h;
        *(half4*)&xl[i] = l;
    }
    if (gtid < NE * DM / 4) {
        int i = gtid * 4;
        float4 v = *(const float4*)&W[i];
        half4 h;
        h.x = (half_t)v.x; h.y = (half_t)v.y;
        h.z = (half_t)v.z; h.w = (half_t)v.w;
        *(half4*)&wh[i] = h;
    }
}

// ---------------------------------------------------------------------------
// QKV projection, fp16 MFMA, hi/lo-split x (exact x, only W rounded).
// Inputs pre-converted by prep -> staging is pure half8 copies.
// Epilogue: q(*0.125)/k scatter; v transposes through LDS -> coalesced vt.
// ---------------------------------------------------------------------------
__global__ __launch_bounds__(256) void qkv_proj(const half_t* __restrict__ xh,
                                                const half_t* __restrict__ xl,
                                                const half_t* __restrict__ whg,
                                                const float* __restrict__ bias,
                                                half_t* __restrict__ qh,
                                                half_t* __restrict__ kh,
                                                half_t* __restrict__ vt) {
    __shared__ __align__(16) half_t Xh[64 * KPAD];
    __shared__ __align__(16) half_t Xl[64 * KPAD];
    __shared__ __align__(16) half_t Wh[64 * KPAD];

    const int rb   = blockIdx.x * 64;
    const int nb   = blockIdx.y * 64;
    const int tid  = threadIdx.x;
    const int wid  = tid >> 6;
    const int lane = tid & 63;
    const int quad = lane >> 4;
    const int col  = lane & 15;

    floatx4 acc[4];
    #pragma unroll
    for (int t = 0; t < 4; ++t) acc[t] = (floatx4){0.f, 0.f, 0.f, 0.f};

    for (int k0 = 0; k0 < DM; k0 += 64) {
        __syncthreads();
        #pragma unroll
        for (int i = 0; i < 2; ++i) {
            int gi = tid + 256 * i;        // 0..511
            int r  = gi >> 3;              // 0..63
            int c8 = (gi & 7) * 8;         // 0..56
            *(half8*)&Xh[r * KPAD + c8] = *(const half8*)&xh[(size_t)(rb + r) * DM + k0 + c8];
            *(half8*)&Xl[r * KPAD + c8] = *(const half8*)&xl[(size_t)(rb + r) * DM + k0 + c8];
            *(half8*)&Wh[r * KPAD + c8] = *(const half8*)&whg[(size_t)(nb + r) * DM + k0 + c8];
        }
        __syncthreads();

        half8 ah0 = *(const half8*)&Xh[(wid * 16 + col) * KPAD + quad * 8];
        half8 ah1 = *(const half8*)&Xh[(wid * 16 + col) * KPAD + 32 + quad * 8];
        half8 al0 = *(const half8*)&Xl[(wid * 16 + col) * KPAD + quad * 8];
        half8 al1 = *(const half8*)&Xl[(wid * 16 + col) * KPAD + 32 + quad * 8];

        #pragma unroll
        for (int t = 0; t < 4; ++t) {
            half8 bh0 = *(const half8*)&Wh[(t * 16 + col) * KPAD + quad * 8];
            half8 bh1 = *(const half8*)&Wh[(t * 16 + col) * KPAD + 32 + quad * 8];
            acc[t] = __builtin_amdgcn_mfma_f32_16x16x32_f16(ah0, bh0, acc[t], 0, 0, 0);
            acc[t] = __builtin_amdgcn_mfma_f32_16x16x32_f16(ah1, bh1, acc[t], 0, 0, 0);
            acc[t] = __builtin_amdgcn_mfma_f32_16x16x32_f16(al0, bh0, acc[t], 0, 0, 0);
            acc[t] = __builtin_amdgcn_mfma_f32_16x16x32_f16(al1, bh1, acc[t], 0, 0, 0);
        }
    }

    const int part = nb >> 8;           // block-uniform: 0=q 1=k 2=v
    const int mloc = wid * 16 + quad * 4;
    if (part != 2) {
        #pragma unroll
        for (int t = 0; t < 4; ++t) {
            int e    = nb + t * 16 + col;
            float be = bias[e];
            int dm   = e & 255;
            int h    = dm >> 6;
            int dh   = dm & 63;
            #pragma unroll
            for (int r = 0; r < 4; ++r) {
                int row = rb + mloc + r;
                int b   = row >> 11;
                int s   = row & 2047;
                int bh_ = b * NH + h;
                float val = acc[t][r] + be;
                if (part == 0) {
                    qh[((size_t)bh_ * SS + s) * DH + dh] = (half_t)(val * 0.125f);
                } else {
                    kh[((size_t)bh_ * SS + s) * DH + dh] = (half_t)val;
                }
            }
        }
    } else {
        __syncthreads();
        #pragma unroll
        for (int t = 0; t < 4; ++t) {
            int e    = nb + t * 16 + col;
            float be = bias[e];
            #pragma unroll
            for (int r = 0; r < 4; ++r)
                Xh[(t * 16 + col) * KPAD + mloc + r] = (half_t)(acc[t][r] + be);
        }
        __syncthreads();
        const int b   = rb >> 11;
        const int s0  = rb & 2047;
        const int h   = (nb >> 6) & 3;
        const int bh_ = b * NH + h;
        #pragma unroll
        for (int i = 0; i < 2; ++i) {
            int idx = tid + 256 * i;
            int rr  = idx >> 3;
            int cc8 = (idx & 7) * 8;
            *(half8*)&vt[((size_t)bh_ * DH + rr) * SS + s0 + cc8] =
                *(const half8*)&Xh[rr * KPAD + cc8];
        }
    }
}

// ---------------------------------------------------------------------------
// Flash attention, fp16 MFMA, S^T trick, split-K(2), 32 q rows per wave.
// Block = 128 thr (2 waves) covers 64 q rows; grid (SS/64, BH, 2) = 1024.
// Every ak/bv LDS fragment feeds BOTH q-strips (2x MFMA per LDS byte).
// K/V tiles register-double-buffered across the compute phase.
// Writes normalized partial O (fp16) + m,l stats per kz half.
// ---------------------------------------------------------------------------
__global__ __launch_bounds__(128) void attn(const half_t* __restrict__ qh,
                                            const half_t* __restrict__ kh,
                                            const half_t* __restrict__ vt,
                                            half_t* __restrict__ pO,
                                            float* __restrict__ mst,
                                            float* __restrict__ lst) {
    __shared__ __align__(16) half_t Ks[64 * KPAD];    // [kr][d]
    __shared__ __align__(16) half_t Vts[64 * KPAD];   // [d][kr]

    const int q0   = blockIdx.x * 64;
    const int bh   = blockIdx.y;
    const int kz   = blockIdx.z;
    const size_t base = (size_t)bh * SS * DH;
    const int tid  = threadIdx.x;
    const int wid  = tid >> 6;    // 0..1
    const int lane = tid & 63;
    const int quad = lane >> 4;
    const int col  = lane & 15;
    const int ktBeg = kz * (SS / 2);
    const int ktEnd = ktBeg + (SS / 2);

    int srr[4], scc[4];
    #pragma unroll
    for (int i = 0; i < 4; ++i) {
        int gi = tid + 128 * i;    // 0..511
        srr[i] = gi >> 3;          // 0..63
        scc[i] = (gi & 7) * 8;     // 0..56
    }

    // Q B-frags: 2 strips of 16 q rows (pre-scaled by 0.125)
    half8 bq[2][2];
    #pragma unroll
    for (int st = 0; st < 2; ++st) {
        int s = q0 + wid * 32 + st * 16 + col;
        bq[st][0] = *(const half8*)&qh[base + (size_t)s * DH + quad * 8];
        bq[st][1] = *(const half8*)&qh[base + (size_t)s * DH + 32 + quad * 8];
    }

    // Preload tile ktBeg into cur regs
    half8 ck[4], cv[4], nk[4], nv[4];
    #pragma unroll
    for (int i = 0; i < 4; ++i) {
        ck[i] = *(const half8*)&kh[base + (size_t)(ktBeg + srr[i]) * DH + scc[i]];
        cv[i] = *(const half8*)&vt[base + (size_t)srr[i] * SS + ktBeg + scc[i]];
        nk[i] = ck[i];
        nv[i] = cv[i];
    }

    float m_i[2] = {-3.0e38f, -3.0e38f};
    float l_i[2] = {0.f, 0.f};
    floatx4 o[2][4];
    #pragma unroll
    for (int st = 0; st < 2; ++st)
        #pragma unroll
        for (int dt = 0; dt < 4; ++dt) o[st][dt] = (floatx4){0.f, 0.f, 0.f, 0.f};

    for (int kt = ktBeg; kt < ktEnd; kt += 64) {
        __syncthreads();
        #pragma unroll
        for (int i = 0; i < 4; ++i) {
            *(half8*)&Ks[srr[i] * KPAD + scc[i]]  = ck[i];
            *(half8*)&Vts[srr[i] * KPAD + scc[i]] = cv[i];
        }
        __syncthreads();

        // Prefetch next tile (in flight across compute)
        const int ktn = kt + 64;
        if (ktn < ktEnd) {
            #pragma unroll
            for (int i = 0; i < 4; ++i) {
                nk[i] = *(const half8*)&kh[base + (size_t)(ktn + srr[i]) * DH + scc[i]];
                nv[i] = *(const half8*)&vt[base + (size_t)srr[i] * SS + ktn + scc[i]];
            }
        }

        // S^T = K · Q^T for both strips (ak frags shared)
        floatx4 sc[2][4];
        #pragma unroll
        for (int t = 0; t < 4; ++t) {
            half8 ak0 = *(const half8*)&Ks[(t * 16 + col) * KPAD + quad * 8];
            half8 ak1 = *(const half8*)&Ks[(t * 16 + col) * KPAD + 32 + quad * 8];
            #pragma unroll
            for (int st = 0; st < 2; ++st) {
                floatx4 c = (floatx4){0.f, 0.f, 0.f, 0.f};
                c = __builtin_amdgcn_mfma_f32_16x16x32_f16(ak0, bq[st][0], c, 0, 0, 0);
                c = __builtin_amdgcn_mfma_f32_16x16x32_f16(ak1, bq[st][1], c, 0, 0, 0);
                sc[st][t] = c;
            }
        }

        // Online softmax per strip
        half4 pa[2][4];
        #pragma unroll
        for (int st = 0; st < 2; ++st) {
            float mloc = -3.0e38f;
            #pragma unroll
            for (int t = 0; t < 4; ++t)
                #pragma unroll
                for (int r = 0; r < 4; ++r)
                    mloc = fmaxf(mloc, sc[st][t][r]);
            mloc = fmaxf(mloc, __shfl_xor(mloc, 16));
            mloc = fmaxf(mloc, __shfl_xor(mloc, 32));
            float m_new = fmaxf(m_i[st], mloc);
            float alpha = __expf(m_i[st] - m_new);
            m_i[st] = m_new;

            float rsum = 0.f;
            #pragma unroll
            for (int t = 0; t < 4; ++t) {
                float p0 = __expf(sc[st][t][0] - m_new);
                float p1 = __expf(sc[st][t][1] - m_new);
                float p2 = __expf(sc[st][t][2] - m_new);
                float p3 = __expf(sc[st][t][3] - m_new);
                rsum += p0 + p1 + p2 + p3;
                pa[st][t] = (half4){(half_t)p0, (half_t)p1, (half_t)p2, (half_t)p3};
            }
            rsum += __shfl_xor(rsum, 16);
            rsum += __shfl_xor(rsum, 32);
            l_i[st] = l_i[st] * alpha + rsum;

            float ar[4];
            #pragma unroll
            for (int i = 0; i < 4; ++i) ar[i] = __shfl(alpha, quad * 4 + i);
            #pragma unroll
            for (int dt = 0; dt < 4; ++dt)
                #pragma unroll
                for (int i = 0; i < 4; ++i)
                    o[st][dt][i] *= ar[i];
        }

        // O += P · V  (bv frags shared by both strips)
        #pragma unroll
        for (int t = 0; t < 4; ++t) {
            #pragma unroll
            for (int dt = 0; dt < 4; ++dt) {
                half4 bv = *(const half4*)&Vts[(dt * 16 + col) * KPAD + t * 16 + quad * 4];
                #pragma unroll
                for (int st = 0; st < 2; ++st)
                    o[st][dt] = __builtin_amdgcn_mfma_f32_16x16x16f16(pa[st][t], bv, o[st][dt], 0, 0, 0);
            }
        }

        #pragma unroll
        for (int i = 0; i < 4; ++i) { ck[i] = nk[i]; cv[i] = nv[i]; }
    }

    // Epilogue: normalized partial O (fp16) + stats
    const size_t pbase = (size_t)kz * HEAD_ELEMS + base;
    #pragma unroll
    for (int st = 0; st < 2; ++st) {
        float inv = 1.0f / l_i[st];
        float ir[4];
        #pragma unroll
        for (int i = 0; i < 4; ++i) ir[i] = __shfl(inv, quad * 4 + i);
        #pragma unroll
        for (int dt = 0; dt < 4; ++dt)
            #pragma unroll
            for (int i = 0; i < 4; ++i) {
                int row = q0 + wid * 32 + st * 16 + quad * 4 + i;
                pO[pbase + (size_t)row * DH + dt * 16 + col] = (half_t)(o[st][dt][i] * ir[i]);
            }
        if (quad == 0) {
            int row = q0 + wid * 32 + st * 16 + col;
            int idx = kz * NQROWS + bh * SS + row;
            mst[idx] = m_i[st];
            lst[idx] = l_i[st];
        }
    }
}

// ---------------------------------------------------------------------------
// merge: combine the two kz partials. 262144 threads, 8 d-elems each.
// ---------------------------------------------------------------------------
__global__ __launch_bounds__(256) void merge(const half_t* __restrict__ pO,
                                             const float* __restrict__ mst,
                                             const float* __restrict__ lst,
                                             float* __restrict__ out) {
    int gid = blockIdx.x * 256 + threadIdx.x;   // 0..262143
    int row = gid >> 3;                         // 0..32767 (bh*SS + s)
    int dc  = (gid & 7) * 8;
    float m1 = mst[row], m2 = mst[NQROWS + row];
    float l1 = lst[row], l2 = lst[NQROWS + row];
    float M  = fmaxf(m1, m2);
    float w1 = l1 * __expf(m1 - M);
    float w2 = l2 * __expf(m2 - M);
    float inv = 1.0f / (w1 + w2);
    float a = w1 * inv, b = w2 * inv;
    half8 o1 = *(const half8*)&pO[(size_t)row * DH + dc];
    half8 o2 = *(const half8*)&pO[(size_t)HEAD_ELEMS + (size_t)row * DH + dc];
    float4 r0, r1;
    r0.x = a * (float)o1[0] + b * (float)o2[0];
    r0.y = a * (float)o1[1] + b * (float)o2[1];
    r0.z = a * (float)o1[2] + b * (float)o2[2];
    r0.w = a * (float)o1[3] + b * (float)o2[3];
    r1.x = a * (float)o1[4] + b * (float)o2[4];
    r1.y = a * (float)o1[5] + b * (float)o2[5];
    r1.z = a * (float)o1[6] + b * (float)o2[6];
    r1.w = a * (float)o1[7] + b * (float)o2[7];
    *(float4*)&out[(size_t)row * DH + dc]     = r0;
    *(float4*)&out[(size_t)row * DH + dc + 4] = r1;
}

extern "C" void kernel_launch(void* const* d_in, const int* in_sizes, int n_in,
                              void* d_out, int out_size, void* d_ws, size_t ws_size,
                              hipStream_t stream) {
    const float* x  = (const float*)d_in[0];   // [4,2048,256]
    const float* Wq = (const float*)d_in[1];   // [768,256]
    const float* bq = (const float*)d_in[2];   // [768]
    float* out = (float*)d_out;                // [4,4,2048,64]

    // ws layout (half_t units):
    //   qh 0..2M | kh 2M..4M | vt 4M..6M | xh 6M..8M | xl 8M..10M | Wh 10M..10.19M
    //   pO[2] aliases xh/xl: 6M..10M (xh/xl dead once qkv_proj finishes)
    //   stats f32 after Wh region (Wh dead during attn)
    half_t* qh  = (half_t*)d_ws;
    half_t* kh  = qh + (size_t)HEAD_ELEMS;
    half_t* vt  = kh + (size_t)HEAD_ELEMS;
    half_t* xh  = vt + (size_t)HEAD_ELEMS;
    half_t* xl  = xh + (size_t)HEAD_ELEMS;
    half_t* whp = xl + (size_t)HEAD_ELEMS;             // 196608 halfs
    half_t* pO  = xh;                                  // alias: 2 x HEAD_ELEMS halfs
    float*  mst = (float*)((char*)d_ws + 21364736);    // 2*32768 floats
    float*  lst = mst + 2 * NQROWS;

    prep<<<2048, 256, 0, stream>>>(x, Wq, xh, xl, whp);
    qkv_proj<<<dim3(NROW / 64, NE / 64), 256, 0, stream>>>(xh, xl, whp, bq, qh, kh, vt);
    attn<<<dim3(SS / 64, BH, 2), 128, 0, stream>>>(qh, kh, vt, pO, mst, lst);
    merge<<<1024, 256, 0, stream>>>(pO, mst, lst, out);
}